// Round 8
// baseline (67.370 us; speedup 1.0000x reference)
//
#include <hip/hip_runtime.h>

// k_full = zero-pad(key[..., :64] -> 128), same for value. [8,8,4096,128] f32.
// Row = 128 f32 = 32 float4; first 16 f4 copied (input idx == output idx),
// last 16 f4 zeroed.  Dense slot j -> half-row f4 index o = (j>>4)*32+(j&15).
//
// Staggered two-phase schedule: even blocks do {zero-fill, copy}, odd blocks
// do {copy, zero-fill}. The HBM bus sees a continuous blended read/write mix
// (no device-wide write-only prologue). Temporal loads (L3-resident input
// across graph replays), NT stores (no-allocate -> don't evict input).

typedef float f4_t __attribute__((ext_vector_type(4)));

__device__ __forceinline__ void do_fill(f4_t* __restrict__ out, long n_f4,
                                        long n_half, long tid, long stride) {
  const f4_t zero = (f4_t)(0.f);
  for (long z = tid; z < n_half; z += stride) {
    const long o = ((z >> 4) << 5) | (z & 15);
    __builtin_nontemporal_store(zero, &out[o + 16]);
    __builtin_nontemporal_store(zero, &out[n_f4 + o + 16]);
  }
}

__device__ __forceinline__ void do_copy(const f4_t* __restrict__ k_in,
                                        const f4_t* __restrict__ v_in,
                                        f4_t* __restrict__ out, long n_f4,
                                        long n_half, long tid, long stride) {
  for (long j = tid; j < n_half; j += stride) {
    const long o = ((j >> 4) << 5) | (j & 15);
    f4_t kv = k_in[o];
    f4_t vv = v_in[o];
    __builtin_nontemporal_store(kv, &out[o]);
    __builtin_nontemporal_store(vv, &out[n_f4 + o]);
  }
}

__global__ __launch_bounds__(256) void kvcache_pad_stagger(
    const f4_t* __restrict__ k_in,
    const f4_t* __restrict__ v_in,
    f4_t* __restrict__ out, long n_f4, long n_half) {
  const long tid = (long)blockIdx.x * blockDim.x + threadIdx.x;
  const long stride = (long)gridDim.x * blockDim.x;
  if (blockIdx.x & 1) {
    do_copy(k_in, v_in, out, n_f4, n_half, tid, stride);
    do_fill(out, n_f4, n_half, tid, stride);
  } else {
    do_fill(out, n_f4, n_half, tid, stride);
    do_copy(k_in, v_in, out, n_f4, n_half, tid, stride);
  }
}

extern "C" void kernel_launch(void* const* d_in, const int* in_sizes, int n_in,
                              void* d_out, int out_size, void* d_ws, size_t ws_size,
                              hipStream_t stream) {
  const f4_t* k_in = (const f4_t*)d_in[0];
  const f4_t* v_in = (const f4_t*)d_in[1];
  f4_t* out = (f4_t*)d_out;

  const long n_f4 = (long)in_sizes[0] / 4;  // 8388608
  const long n_half = n_f4 / 2;             // 4194304

  kvcache_pad_stagger<<<2048, 256, 0, stream>>>(k_in, v_in, out, n_f4, n_half);
}

// Round 9
// 62.903 us; speedup vs baseline: 1.0710x; 1.0710x over previous
//
#include <hip/hip_runtime.h>

// k_full = zero-pad(key[..., :64] -> 128), same for value. [8,8,4096,128] f32.
// Row = 128 f32 = 32 float4; first 16 f4 copied (input idx == output idx),
// last 16 f4 zeroed.  Dense slot j -> half-row f4 index o = (j>>4)*32+(j&15).
//
// BEST (round 7, 62.3 us = 6.46 TB/s effective on 402.7 MB compulsory):
// Single launch, two device-wide phases per block (no barrier):
//   A: zero-fill this block's pad slots (pure NT writes, ~7 TB/s fill regime)
//   B: copy this block's data slots (temporal reads -> L3-resident across
//      graph replays; NT writes -> no-allocate, don't evict the input)
// Phase separation beats blending (round 8 stagger: 67.4 us) — HBM
// read/write turnaround cost favors direction-segregated phases.

typedef float f4_t __attribute__((ext_vector_type(4)));

__global__ __launch_bounds__(256) void kvcache_pad_fused(
    const f4_t* __restrict__ k_in,
    const f4_t* __restrict__ v_in,
    f4_t* __restrict__ out, long n_f4, long n_half) {
  const f4_t zero = (f4_t)(0.f);
  const long tid = (long)blockIdx.x * blockDim.x + threadIdx.x;
  const long stride = (long)gridDim.x * blockDim.x;

  // Phase A: pure-write zero fill of pad halves (134 MB NT writes)
  for (long z = tid; z < n_half; z += stride) {
    const long o = ((z >> 4) << 5) | (z & 15);
    __builtin_nontemporal_store(zero, &out[o + 16]);
    __builtin_nontemporal_store(zero, &out[n_f4 + o + 16]);
  }

  // Phase B: copy first halves (temporal reads, NT writes)
  for (long j = tid; j < n_half; j += stride) {
    const long o = ((j >> 4) << 5) | (j & 15);
    f4_t kv = k_in[o];
    f4_t vv = v_in[o];
    __builtin_nontemporal_store(kv, &out[o]);
    __builtin_nontemporal_store(vv, &out[n_f4 + o]);
  }
}

extern "C" void kernel_launch(void* const* d_in, const int* in_sizes, int n_in,
                              void* d_out, int out_size, void* d_ws, size_t ws_size,
                              hipStream_t stream) {
  const f4_t* k_in = (const f4_t*)d_in[0];
  const f4_t* v_in = (const f4_t*)d_in[1];
  f4_t* out = (f4_t*)d_out;

  const long n_f4 = (long)in_sizes[0] / 4;  // 8388608
  const long n_half = n_f4 / 2;             // 4194304

  kvcache_pad_fused<<<2048, 256, 0, stream>>>(k_in, v_in, out, n_f4, n_half);
}